// Round 10
// baseline (1467.187 us; speedup 1.0000x reference)
//
#include <hip/hip_runtime.h>
#include <hip/hip_bf16.h>
#include <math.h>

typedef __bf16 bf16;
typedef bf16  bf16x8 __attribute__((ext_vector_type(8)));
typedef bf16  bf16x4 __attribute__((ext_vector_type(4)));
typedef float f32x4  __attribute__((ext_vector_type(4)));

#define TOKENS 4096
#define DM 2048
#define FF 1024
#define NE 16
#define SH_BASE 12288        // routed padded slot region [0,12288), shared [12288,20480)

// ---- workspace layout (bytes) ----
#define WS_CNT    0
#define WS_POS    64
#define WS_BASE   128
#define WS_TOPKW  256
#define WS_TOPKI  33024
#define WS_TSLOT  65792
#define WS_LIST   98560
#define WS_XB     180480
#define WS_H      16957696
#define WS_Y      58900736
#define WS_B1R    142786816   // [16][2F][D] bf16, fused gate/up (32-row interleave)
#define WS_B1S    277004544   // [2][2F][D]
#define WS_W2TR   293781760   // [16][D][F]
#define WS_W2TS   360890624   // [2][D][F]
// total 369279232

__device__ __forceinline__ bf16 f2bf(float f) {
  unsigned u = __builtin_bit_cast(unsigned, f);
  u += 0x7fffu + ((u >> 16) & 1u);          // RNE
  unsigned short h = (unsigned short)(u >> 16);
  return __builtin_bit_cast(bf16, h);
}

typedef const __attribute__((address_space(1))) void* gas_t;
typedef __attribute__((address_space(3))) void* las_t;
__device__ __forceinline__ void load_lds16(const bf16* g, bf16* l) {
  // async global->LDS, 16 B per lane; LDS dst is wave-uniform base + lane*16
  __builtin_amdgcn_global_load_lds((gas_t)g, (las_t)l, 16, 0, 0);
}

// ---------------- merged plain transpose+convert: w2 [Z][F][D] f32 -> [Z][D][F] bf16 ----
// store phase: 16 B bf16x8 per store (2/thread); LDS col-reads are 2-way bank
// aliased (free): bank = (u*8+i+c) mod 32, each hit by exactly 2 lanes.
__global__ void transpose_cvt_all_kernel(const float* __restrict__ rw2, const float* __restrict__ sw2,
                                         bf16* __restrict__ W2TR, bf16* __restrict__ W2TS) {
  __shared__ float tile[64][65];
  const int z = blockIdx.z;
  const float* src_base;
  bf16* dst_base;
  if (z < NE) { src_base = rw2 + (size_t)z * FF * DM; dst_base = W2TR + (size_t)z * DM * FF; }
  else { const int s = z - NE; src_base = sw2 + (size_t)s * FF * DM; dst_base = W2TS + (size_t)s * DM * FF; }
  const int R = FF, C = DM;
  const int c0 = blockIdx.x * 64, r0 = blockIdx.y * 64;
  const int t = threadIdx.x;
  const int lr = t >> 2;            // 0..63 row
  const int lc = (t & 3) * 4;       // col quad base
  const float* src = src_base + (size_t)(r0 + lr) * C + c0;
#pragma unroll
  for (int j = 0; j < 4; j++) {
    const f32x4 v = *(const f32x4*)(src + lc + j * 16);
    tile[lr][lc + j * 16 + 0] = v[0];
    tile[lr][lc + j * 16 + 1] = v[1];
    tile[lr][lc + j * 16 + 2] = v[2];
    tile[lr][lc + j * 16 + 3] = v[3];
  }
  __syncthreads();
  const int c = t >> 2;             // output row (source col), 0..63
  const int u2 = (t & 3) * 2;       // 8-elem chunk base
#pragma unroll
  for (int v = 0; v < 2; v++) {
    const int u = u2 + v;
    bf16x8 o;
#pragma unroll
    for (int i = 0; i < 8; i++) o[i] = f2bf(tile[u * 8 + i][c]);
    *(bf16x8*)(dst_base + (size_t)(c0 + c) * R + r0 + u * 8) = o;
  }
}

// ---------------- merged fused transpose: {rg,rw1,sg,sw1} [D][F] f32 -> B1 [2F][D] bf16 ----
// fused row for source col f: fr = (f>>4)*32 + half*16 + (f&15)
__global__ void transpose_cvt_fused_all_kernel(
    const float* __restrict__ rg, const float* __restrict__ rw1,
    const float* __restrict__ sg, const float* __restrict__ sw1,
    bf16* __restrict__ B1R, bf16* __restrict__ B1S) {
  __shared__ float tile[64][65];
  const int z = blockIdx.z;                 // 0..35
  const int half = (z >= 18) ? 1 : 0;
  const int ze = z - 18 * half;
  const float* src_base;
  bf16* dst_base;
  if (ze < NE) {
    src_base = (half ? rw1 : rg) + (size_t)ze * DM * FF;
    dst_base = B1R + (size_t)ze * (2 * FF) * DM;
  } else {
    const int s = ze - NE;
    src_base = (half ? sw1 : sg) + (size_t)s * DM * FF;
    dst_base = B1S + (size_t)s * (2 * FF) * DM;
  }
  const int c0 = blockIdx.x * 64, r0 = blockIdx.y * 64;  // c over F, r over D
  const int t = threadIdx.x;
  const int lr = t >> 2;
  const int lc = (t & 3) * 4;
  const float* src = src_base + (size_t)(r0 + lr) * FF + c0;
#pragma unroll
  for (int j = 0; j < 4; j++) {
    const f32x4 v = *(const f32x4*)(src + lc + j * 16);
    tile[lr][lc + j * 16 + 0] = v[0];
    tile[lr][lc + j * 16 + 1] = v[1];
    tile[lr][lc + j * 16 + 2] = v[2];
    tile[lr][lc + j * 16 + 3] = v[3];
  }
  __syncthreads();
  const int c = t >> 2;             // source col within tile, 0..63
  const int u2 = (t & 3) * 2;
  const int f = c0 + c;
  const int fr = ((f >> 4) << 5) + half * 16 + (f & 15);
#pragma unroll
  for (int v = 0; v < 2; v++) {
    const int u = u2 + v;
    bf16x8 o;
#pragma unroll
    for (int i = 0; i < 8; i++) o[i] = f2bf(tile[u * 8 + i][c]);
    *(bf16x8*)(dst_base + (size_t)fr * DM + r0 + u * 8) = o;
  }
}

// ---------------- router: LDS-tiled GEMV, fused x->bf16 conversion ----------------
#define RT_TOK 16
#define RT_DK  256
#define RT_PITCH (RT_DK + 4)

__global__ __launch_bounds__(256) void router_kernel(
    const float* __restrict__ x, const float* __restrict__ wa,
    float* __restrict__ topk_w, int* __restrict__ topk_i,
    int* __restrict__ cnt, bf16* __restrict__ xb) {
  __shared__ float xs[RT_TOK][RT_PITCH];
  __shared__ float was[NE][RT_PITCH];
  __shared__ float aff[RT_TOK][17];

  const int tid = threadIdx.x;
  const int t = tid >> 4;
  const int e = tid & 15;
  const int t0 = blockIdx.x * RT_TOK;

  f32x4 acc4 = {0.f, 0.f, 0.f, 0.f};

  for (int d0 = 0; d0 < DM; d0 += RT_DK) {
    __syncthreads();
    {
      const int r = tid >> 4;
      const int c4 = (tid & 15) * 4;
      const float* src = x + (size_t)(t0 + r) * DM + d0;
      bf16* dstx = xb + (size_t)(t0 + r) * DM + d0;
#pragma unroll
      for (int j = 0; j < 4; j++) {
        const f32x4 v = *(const f32x4*)(src + c4 + j * 64);
        *(f32x4*)(&xs[r][c4 + j * 64]) = v;
        bf16x4 o;
        o[0] = f2bf(v[0]); o[1] = f2bf(v[1]); o[2] = f2bf(v[2]); o[3] = f2bf(v[3]);
        *(bf16x4*)(dstx + c4 + j * 64) = o;       // fused cvt_x
      }
    }
    {
      const int e2 = tid & 15;
      const int dd = (tid >> 4) * 16;
#pragma unroll
      for (int j = 0; j < 16; j++)
        was[e2][dd + j] = wa[(size_t)(d0 + dd + j) * NE + e2];
    }
    __syncthreads();
#pragma unroll 16
    for (int d = 0; d < RT_DK; d += 4) {
      const f32x4 xv = *(const f32x4*)(&xs[t][d]);
      const f32x4 wv = *(const f32x4*)(&was[e][d]);
      acc4 += xv * wv;
    }
  }

  const float a = acc4[0] + acc4[1] + acc4[2] + acc4[3];
  aff[t][e] = 1.f / (1.f + expf(-a));
  __syncthreads();

  if (e == 0) {
    float b0 = -1e30f, b1 = -1e30f; int i0 = 0, i1 = 0;
    for (int i = 0; i < NE; i++) {
      const float v = aff[t][i];
      if (v > b0) { b1 = b0; i1 = i0; b0 = v; i0 = i; }
      else if (v > b1) { b1 = v; i1 = i; }
    }
    const int tok = t0 + t;
    const float inv = 1.f / (b0 + b1);
    topk_w[tok * 2] = b0 * inv;  topk_w[tok * 2 + 1] = b1 * inv;
    topk_i[tok * 2] = i0;        topk_i[tok * 2 + 1] = i1;
    atomicAdd(&cnt[i0], 1);      atomicAdd(&cnt[i1], 1);
  }
}

__global__ void prefix_kernel(const int* __restrict__ cnt, int* __restrict__ base) {
  if (threadIdx.x == 0) {
    int acc = 0;
    for (int e = 0; e < NE; e++) { base[e] = acc; acc += (cnt[e] + 127) & ~127; }
    base[NE] = SH_BASE;
    base[NE + 1] = SH_BASE + TOKENS;
  }
}

__global__ void build_lists_kernel(const int* __restrict__ topk_i, const int* __restrict__ base,
                                   int* __restrict__ pos, int* __restrict__ list,
                                   int* __restrict__ token_slot) {
  const int t = blockIdx.x * 256 + threadIdx.x;
  if (t >= TOKENS) return;
#pragma unroll
  for (int k = 0; k < 2; k++) {
    const int e = topk_i[t * 2 + k];
    const int p = atomicAdd(&pos[e], 1);
    const int slot = base[e] + p;
    list[slot] = t;
    token_slot[t * 2 + k] = slot;
  }
  list[SH_BASE + t] = t;
  list[SH_BASE + TOKENS + t] = t;
}

// ===== balanced per-expert XCD-chunked tile map (round-4/7 verified) =====
#define GEMM_GRID_MAX 2304   // 16 * (80 routed-max + 64 shared) m-tiles

__device__ __forceinline__ bool map_tile(int flat, const int* __restrict__ cnt,
                                         int& e, int& my, int& nx) {
  int o = 0;
  for (int ee = 0; ee < NE + 2; ++ee) {
    const int ce = (ee < NE) ? cnt[ee] : TOKENS;
    const int me = (ce + 127) >> 7;
    const int Te = me << 4;
    if (flat < o + Te) {
      const int l = flat - o;
      const int s = (l & 7) * (me << 1) + (l >> 3);
      nx = s / me;
      my = s - nx * me;
      e = ee;
      return true;
    }
    o += Te;
  }
  return false;
}

// ================= 2-phase 128x128 GEMMs, BK=32, 5 blocks/CU =================
// Verified round-9 structure (2-phase dbuf, BK=32 swizzle, 0 conflicts).
// launch_bounds 4->5: LDS 5 x 32 KB = 160 KB exactly; VGPR 64 << 102 cap.
// Worst case HW schedules 4 (status quo) -> no downside.

// ---------------- GEMM1: fused gate/up B1 ----------------
__global__ __launch_bounds__(256, 5) void gemm1_kernel(
    const bf16* __restrict__ xb, const int* __restrict__ list,
    const int* __restrict__ base, const int* __restrict__ cnt,
    const bf16* __restrict__ B1R, const bf16* __restrict__ B1S,
    const float* __restrict__ rgb, const float* __restrict__ rb1,
    const float* __restrict__ sgb, const float* __restrict__ sb1,
    bf16* __restrict__ H) {
  int e, bmy, bnx;
  if (!map_tile(blockIdx.x, cnt, e, bmy, bnx)) return;
  const int ce = (e < NE) ? cnt[e] : TOKENS;
  const int m0 = bmy * 128;
  const int n0 = bnx * 128;          // over 2*FF fused rows
  const int bse = base[e];

  const bf16* B1; const float *gb, *ub;
  if (e < NE) { B1 = B1R + (size_t)e * (2 * FF) * DM; gb = rgb + e * FF; ub = rb1 + e * FF; }
  else { const int s = e - NE; B1 = B1S + (size_t)s * (2 * FF) * DM; gb = sgb + s * FF; ub = sb1 + s * FF; }

  __shared__ bf16 As[2][128 * 32];   // 16 KB
  __shared__ bf16 Bs[2][128 * 32];   // 16 KB

  const int tid = threadIdx.x, lane = tid & 63, wid = tid >> 6;
  const int m16 = lane & 15, quad = lane >> 4;
  const int wm = (wid & 1) * 64, wn = (wid >> 1) * 64;
  const int rslot = (quad ^ ((m16 >> 1) & 3)) << 3;   // swizzled ds_read granule (elems)

  // staging: thread covers rows srow and 64+srow (granule tid&3)
  const int srow = tid >> 2;                          // 0..63
  const int gsw = (((tid & 3) ^ ((tid >> 3) & 3)) << 3);  // pre-swizzled source granule
  int ra0 = m0 + srow;      if (ra0 >= ce) ra0 = ce - 1;
  int ra1 = m0 + 64 + srow; if (ra1 >= ce) ra1 = ce - 1;
  const bf16* aP0 = xb + (size_t)list[bse + ra0] * DM + gsw;
  const bf16* aP1 = xb + (size_t)list[bse + ra1] * DM + gsw;
  const bf16* bP0 = B1 + (size_t)(n0 + srow) * DM + gsw;
  const bf16* bP1 = B1 + (size_t)(n0 + 64 + srow) * DM + gsw;
  const int d0 = wid * 512;            // wave LDS base, sweep 0 (elems)
  const int d1 = 2048 + wid * 512;     // sweep 1
  const int l8 = lane << 3;

#define G1_STAGE(buf, k)                              \
  {                                                   \
    load_lds16(aP0 + (k), &As[buf][d0 + l8]);         \
    load_lds16(aP1 + (k), &As[buf][d1 + l8]);         \
    load_lds16(bP0 + (k), &Bs[buf][d0 + l8]);         \
    load_lds16(bP1 + (k), &Bs[buf][d1 + l8]);         \
  }

  f32x4 acc[4][4] = {};

  G1_STAGE(0, 0)

  int cur = 0;
  for (int k0 = 0; k0 < DM; k0 += 32) {
    __syncthreads();                 // drains vmcnt -> buf(cur) ready; reads of buf(nxt) done
    if (k0 + 32 < DM) { G1_STAGE(cur ^ 1, k0 + 32) }
    bf16x8 af[4], bfr[4];
#pragma unroll
    for (int i = 0; i < 4; i++) {
      af[i]  = *(const bf16x8*)(&As[cur][(wm + m16 + 16 * i) * 32 + rslot]);
      bfr[i] = *(const bf16x8*)(&Bs[cur][(wn + m16 + 16 * i) * 32 + rslot]);
    }
#pragma unroll
    for (int mi = 0; mi < 4; mi++)
#pragma unroll
      for (int ni = 0; ni < 4; ni++)
        acc[mi][ni] = __builtin_amdgcn_mfma_f32_16x16x32_bf16(af[mi], bfr[ni], acc[mi][ni], 0, 0, 0);
    cur ^= 1;
  }
#undef G1_STAGE

  // epilogue: ni even = gate, ni odd = up, same f range; h = gelu(g)*u
  const int q4 = quad * 4;
  const int fbase = ((n0 + wn) >> 1) + m16;
#pragma unroll
  for (int mi = 0; mi < 4; mi++) {
#pragma unroll
    for (int nj = 0; nj < 2; nj++) {
      const int f = fbase + nj * 16;
      const float gbv = gb[f], ubv = ub[f];
#pragma unroll
      for (int r = 0; r < 4; r++) {
        const int row = m0 + wm + mi * 16 + q4 + r;
        const float g = acc[mi][2 * nj][r] + gbv;
        const float u = acc[mi][2 * nj + 1][r] + ubv;
        const float h = 0.5f * g * (1.f + erff(g * 0.70710678118f)) * u;
        H[(size_t)(bse + row) * FF + f] = f2bf(h);
      }
    }
  }
}

// ---------------- GEMM2: Y = H @ w2 + b2 ----------------
__global__ __launch_bounds__(256, 5) void gemm2_kernel(
    const bf16* __restrict__ Hb, const int* __restrict__ base, const int* __restrict__ cnt,
    const bf16* __restrict__ rw2T, const bf16* __restrict__ sw2T,
    const float* __restrict__ rb2, const float* __restrict__ sb2,
    bf16* __restrict__ Y) {
  int e, bmy, bnx;
  if (!map_tile(blockIdx.x, cnt, e, bmy, bnx)) return;
  const int m0 = bmy * 128;
  const int n0 = bnx * 128;
  const int bse = base[e];

  const bf16* B; const float* bb;
  if (e < NE) { B = rw2T + (size_t)e * DM * FF; bb = rb2 + e * DM; }
  else { const int s = e - NE; B = sw2T + (size_t)s * DM * FF; bb = sb2 + s * DM; }

  __shared__ bf16 As[2][128 * 32];
  __shared__ bf16 Bs[2][128 * 32];

  const int tid = threadIdx.x, lane = tid & 63, wid = tid >> 6;
  const int m16 = lane & 15, quad = lane >> 4;
  const int wm = (wid & 1) * 64, wn = (wid >> 1) * 64;
  const int rslot = (quad ^ ((m16 >> 1) & 3)) << 3;

  const int srow = tid >> 2;
  const int gsw = (((tid & 3) ^ ((tid >> 3) & 3)) << 3);
  const bf16* aP0 = Hb + (size_t)(bse + m0 + srow) * FF + gsw;       // padded rows valid
  const bf16* aP1 = Hb + (size_t)(bse + m0 + 64 + srow) * FF + gsw;
  const bf16* bP0 = B + (size_t)(n0 + srow) * FF + gsw;
  const bf16* bP1 = B + (size_t)(n0 + 64 + srow) * FF + gsw;
  const int d0 = wid * 512;
  const int d1 = 2048 + wid * 512;
  const int l8 = lane << 3;

#define G2_STAGE(buf, k)                              \
  {                                                   \
    load_lds16(aP0 + (k), &As[buf][d0 + l8]);         \
    load_lds16(aP1 + (k), &As[buf][d1 + l8]);         \
    load_lds16(bP0 + (k), &Bs[buf][d0 + l8]);         \
    load_lds16(bP1 + (k), &Bs[buf][d1 + l8]);         \
  }

  f32x4 acc[4][4] = {};

  G2_STAGE(0, 0)

  int cur = 0;
  for (int k0 = 0; k0 < FF; k0 += 32) {
    __syncthreads();
    if (k0 + 32 < FF) { G2_STAGE(cur ^ 1, k0 + 32) }
    bf16x8 af[4], bfr[4];
#pragma unroll
    for (int i = 0; i < 4; i++) {
      af[i]  = *(const bf16x8*)(&As[cur][(wm + m16 + 16 * i) * 32 + rslot]);
      bfr[i] = *(const bf16x8*)(&Bs[cur][(wn + m16 + 16 * i) * 32 + rslot]);
    }
#pragma unroll
    for (int mi = 0; mi < 4; mi++)
#pragma unroll
      for (int ni = 0; ni < 4; ni++)
        acc[mi][ni] = __builtin_amdgcn_mfma_f32_16x16x32_bf16(af[mi], bfr[ni], acc[mi][ni], 0, 0, 0);
    cur ^= 1;
  }
#undef G2_STAGE

  const int q4 = quad * 4;
#pragma unroll
  for (int mi = 0; mi < 4; mi++) {
#pragma unroll
    for (int ni = 0; ni < 4; ni++) {
      const int n = n0 + wn + ni * 16 + m16;
      const float bv = bb[n];
#pragma unroll
      for (int r = 0; r < 4; r++) {
        const int row = m0 + wm + mi * 16 + q4 + r;
        Y[(size_t)(bse + row) * DM + n] = f2bf(acc[mi][ni][r] + bv);
      }
    }
  }
}

// ---------------- combine ----------------
__global__ void combine_kernel(const float* __restrict__ x, const bf16* __restrict__ Y,
                               const int* __restrict__ token_slot, const float* __restrict__ topk_w,
                               float* __restrict__ out) {
  const int t = blockIdx.x;
  const int d = threadIdx.x * 8;
  const int s0 = token_slot[t * 2], s1 = token_slot[t * 2 + 1];
  const float w0 = topk_w[t * 2], w1 = topk_w[t * 2 + 1];
  const bf16x8 ya = *(const bf16x8*)(Y + (size_t)(SH_BASE + t) * DM + d);
  const bf16x8 yb = *(const bf16x8*)(Y + (size_t)(SH_BASE + TOKENS + t) * DM + d);
  const bf16x8 y0 = *(const bf16x8*)(Y + (size_t)s0 * DM + d);
  const bf16x8 y1 = *(const bf16x8*)(Y + (size_t)s1 * DM + d);
  const float* xp = x + (size_t)t * DM + d;
  float* op = out + (size_t)t * DM + d;
#pragma unroll
  for (int j = 0; j < 8; j++)
    op[j] = xp[j] + (float)ya[j] + (float)yb[j] + w0 * (float)y0[j] + w1 * (float)y1[j];
}

extern "C" void kernel_launch(void* const* d_in, const int* in_sizes, int n_in,
                              void* d_out, int out_size, void* d_ws, size_t ws_size,
                              hipStream_t stream) {
  (void)in_sizes; (void)n_in; (void)out_size; (void)ws_size;
  const float* x   = (const float*)d_in[0];
  const float* wa  = (const float*)d_in[1];
  const float* rg  = (const float*)d_in[2];
  const float* rgb = (const float*)d_in[3];
  const float* rw1 = (const float*)d_in[4];
  const float* rb1 = (const float*)d_in[5];
  const float* rw2 = (const float*)d_in[6];
  const float* rb2 = (const float*)d_in[7];
  const float* sg  = (const float*)d_in[8];
  const float* sgb = (const float*)d_in[9];
  const float* sw1 = (const float*)d_in[10];
  const float* sb1 = (const float*)d_in[11];
  const float* sw2 = (const float*)d_in[12];
  const float* sb2 = (const float*)d_in[13];
  float* out = (float*)d_out;

  char* ws = (char*)d_ws;
  int*   cnt        = (int*)(ws + WS_CNT);
  int*   pos        = (int*)(ws + WS_POS);
  int*   basep      = (int*)(ws + WS_BASE);
  float* topk_w     = (float*)(ws + WS_TOPKW);
  int*   topk_i     = (int*)(ws + WS_TOPKI);
  int*   token_slot = (int*)(ws + WS_TSLOT);
  int*   list       = (int*)(ws + WS_LIST);
  bf16*  xb         = (bf16*)(ws + WS_XB);
  bf16*  H          = (bf16*)(ws + WS_H);
  bf16*  Y          = (bf16*)(ws + WS_Y);
  bf16*  B1R        = (bf16*)(ws + WS_B1R);
  bf16*  B1S        = (bf16*)(ws + WS_B1S);
  bf16*  W2TR       = (bf16*)(ws + WS_W2TR);
  bf16*  W2TS       = (bf16*)(ws + WS_W2TS);

  hipMemsetAsync(ws, 0, 128, stream);  // cnt + pos

  router_kernel<<<TOKENS / RT_TOK, 256, 0, stream>>>(x, wa, topk_w, topk_i, cnt, xb);
  prefix_kernel<<<1, 64, 0, stream>>>(cnt, basep);
  build_lists_kernel<<<TOKENS / 256, 256, 0, stream>>>(topk_i, basep, pos, list, token_slot);

  // weight prep (merged): fused gate/up -> B1, plain transpose -> W2T
  transpose_cvt_fused_all_kernel<<<dim3(FF / 64, DM / 64, 36), 256, 0, stream>>>(
      rg, rw1, sg, sw1, B1R, B1S);
  transpose_cvt_all_kernel<<<dim3(DM / 64, FF / 64, 18), 256, 0, stream>>>(
      rw2, sw2, W2TR, W2TS);

  gemm1_kernel<<<GEMM_GRID_MAX, 256, 0, stream>>>(
      xb, list, basep, cnt, B1R, B1S, rgb, rb1, sgb, sb1, H);
  gemm2_kernel<<<GEMM_GRID_MAX, 256, 0, stream>>>(
      H, basep, cnt, W2TR, W2TS, rb2, sb2, Y);
  combine_kernel<<<TOKENS, 256, 0, stream>>>(x, Y, token_slot, topk_w, out);
}

// Round 11
// 880.239 us; speedup vs baseline: 1.6668x; 1.6668x over previous
//
#include <hip/hip_runtime.h>
#include <hip/hip_bf16.h>
#include <math.h>

typedef __bf16 bf16;
typedef bf16  bf16x8 __attribute__((ext_vector_type(8)));
typedef bf16  bf16x4 __attribute__((ext_vector_type(4)));
typedef float f32x4  __attribute__((ext_vector_type(4)));

#define TOKENS 4096
#define DM 2048
#define FF 1024
#define NE 16
#define SH_BASE 12288        // routed padded slot region [0,12288), shared [12288,20480)

// ---- workspace layout (bytes) ----
#define WS_CNT    0
#define WS_POS    64
#define WS_BASE   128
#define WS_TOPKW  256
#define WS_TOPKI  33024
#define WS_TSLOT  65792
#define WS_LIST   98560
#define WS_XB     180480
#define WS_H      16957696
#define WS_Y      58900736
#define WS_B1R    142786816   // [16][2F][D] bf16, fused gate/up (32-row interleave)
#define WS_B1S    277004544   // [2][2F][D]
#define WS_W2TR   293781760   // [16][D][F]
#define WS_W2TS   360890624   // [2][D][F]
// total 369279232

__device__ __forceinline__ bf16 f2bf(float f) {
  unsigned u = __builtin_bit_cast(unsigned, f);
  u += 0x7fffu + ((u >> 16) & 1u);          // RNE
  unsigned short h = (unsigned short)(u >> 16);
  return __builtin_bit_cast(bf16, h);
}

typedef const __attribute__((address_space(1))) void* gas_t;
typedef __attribute__((address_space(3))) void* las_t;
__device__ __forceinline__ void load_lds16(const bf16* g, bf16* l) {
  // async global->LDS, 16 B per lane; LDS dst is wave-uniform base + lane*16
  __builtin_amdgcn_global_load_lds((gas_t)g, (las_t)l, 16, 0, 0);
}

// ---------------- merged plain transpose+convert: w2 [Z][F][D] f32 -> [Z][D][F] bf16 ----
// store phase: 16 B bf16x8 per store (2/thread); LDS col-reads are 2-way bank
// aliased (free): bank = (u*8+i+c) mod 32, each hit by exactly 2 lanes.
__global__ void transpose_cvt_all_kernel(const float* __restrict__ rw2, const float* __restrict__ sw2,
                                         bf16* __restrict__ W2TR, bf16* __restrict__ W2TS) {
  __shared__ float tile[64][65];
  const int z = blockIdx.z;
  const float* src_base;
  bf16* dst_base;
  if (z < NE) { src_base = rw2 + (size_t)z * FF * DM; dst_base = W2TR + (size_t)z * DM * FF; }
  else { const int s = z - NE; src_base = sw2 + (size_t)s * FF * DM; dst_base = W2TS + (size_t)s * DM * FF; }
  const int R = FF, C = DM;
  const int c0 = blockIdx.x * 64, r0 = blockIdx.y * 64;
  const int t = threadIdx.x;
  const int lr = t >> 2;            // 0..63 row
  const int lc = (t & 3) * 4;       // col quad base
  const float* src = src_base + (size_t)(r0 + lr) * C + c0;
#pragma unroll
  for (int j = 0; j < 4; j++) {
    const f32x4 v = *(const f32x4*)(src + lc + j * 16);
    tile[lr][lc + j * 16 + 0] = v[0];
    tile[lr][lc + j * 16 + 1] = v[1];
    tile[lr][lc + j * 16 + 2] = v[2];
    tile[lr][lc + j * 16 + 3] = v[3];
  }
  __syncthreads();
  const int c = t >> 2;             // output row (source col), 0..63
  const int u2 = (t & 3) * 2;       // 8-elem chunk base
#pragma unroll
  for (int v = 0; v < 2; v++) {
    const int u = u2 + v;
    bf16x8 o;
#pragma unroll
    for (int i = 0; i < 8; i++) o[i] = f2bf(tile[u * 8 + i][c]);
    *(bf16x8*)(dst_base + (size_t)(c0 + c) * R + r0 + u * 8) = o;
  }
}

// ---------------- merged fused transpose: {rg,rw1,sg,sw1} [D][F] f32 -> B1 [2F][D] bf16 ----
// fused row for source col f: fr = (f>>4)*32 + half*16 + (f&15)
__global__ void transpose_cvt_fused_all_kernel(
    const float* __restrict__ rg, const float* __restrict__ rw1,
    const float* __restrict__ sg, const float* __restrict__ sw1,
    bf16* __restrict__ B1R, bf16* __restrict__ B1S) {
  __shared__ float tile[64][65];
  const int z = blockIdx.z;                 // 0..35
  const int half = (z >= 18) ? 1 : 0;
  const int ze = z - 18 * half;
  const float* src_base;
  bf16* dst_base;
  if (ze < NE) {
    src_base = (half ? rw1 : rg) + (size_t)ze * DM * FF;
    dst_base = B1R + (size_t)ze * (2 * FF) * DM;
  } else {
    const int s = ze - NE;
    src_base = (half ? sw1 : sg) + (size_t)s * DM * FF;
    dst_base = B1S + (size_t)s * (2 * FF) * DM;
  }
  const int c0 = blockIdx.x * 64, r0 = blockIdx.y * 64;  // c over F, r over D
  const int t = threadIdx.x;
  const int lr = t >> 2;
  const int lc = (t & 3) * 4;
  const float* src = src_base + (size_t)(r0 + lr) * FF + c0;
#pragma unroll
  for (int j = 0; j < 4; j++) {
    const f32x4 v = *(const f32x4*)(src + lc + j * 16);
    tile[lr][lc + j * 16 + 0] = v[0];
    tile[lr][lc + j * 16 + 1] = v[1];
    tile[lr][lc + j * 16 + 2] = v[2];
    tile[lr][lc + j * 16 + 3] = v[3];
  }
  __syncthreads();
  const int c = t >> 2;             // source col within tile, 0..63
  const int u2 = (t & 3) * 2;
  const int f = c0 + c;
  const int fr = ((f >> 4) << 5) + half * 16 + (f & 15);
#pragma unroll
  for (int v = 0; v < 2; v++) {
    const int u = u2 + v;
    bf16x8 o;
#pragma unroll
    for (int i = 0; i < 8; i++) o[i] = f2bf(tile[u * 8 + i][c]);
    *(bf16x8*)(dst_base + (size_t)fr * DM + r0 + u * 8) = o;
  }
}

// ---------------- router: LDS-tiled GEMV, fused x->bf16 conversion ----------------
#define RT_TOK 16
#define RT_DK  256
#define RT_PITCH (RT_DK + 4)

__global__ __launch_bounds__(256) void router_kernel(
    const float* __restrict__ x, const float* __restrict__ wa,
    float* __restrict__ topk_w, int* __restrict__ topk_i,
    int* __restrict__ cnt, bf16* __restrict__ xb) {
  __shared__ float xs[RT_TOK][RT_PITCH];
  __shared__ float was[NE][RT_PITCH];
  __shared__ float aff[RT_TOK][17];

  const int tid = threadIdx.x;
  const int t = tid >> 4;
  const int e = tid & 15;
  const int t0 = blockIdx.x * RT_TOK;

  f32x4 acc4 = {0.f, 0.f, 0.f, 0.f};

  for (int d0 = 0; d0 < DM; d0 += RT_DK) {
    __syncthreads();
    {
      const int r = tid >> 4;
      const int c4 = (tid & 15) * 4;
      const float* src = x + (size_t)(t0 + r) * DM + d0;
      bf16* dstx = xb + (size_t)(t0 + r) * DM + d0;
#pragma unroll
      for (int j = 0; j < 4; j++) {
        const f32x4 v = *(const f32x4*)(src + c4 + j * 64);
        *(f32x4*)(&xs[r][c4 + j * 64]) = v;
        bf16x4 o;
        o[0] = f2bf(v[0]); o[1] = f2bf(v[1]); o[2] = f2bf(v[2]); o[3] = f2bf(v[3]);
        *(bf16x4*)(dstx + c4 + j * 64) = o;       // fused cvt_x
      }
    }
    {
      const int e2 = tid & 15;
      const int dd = (tid >> 4) * 16;
#pragma unroll
      for (int j = 0; j < 16; j++)
        was[e2][dd + j] = wa[(size_t)(d0 + dd + j) * NE + e2];
    }
    __syncthreads();
#pragma unroll 16
    for (int d = 0; d < RT_DK; d += 4) {
      const f32x4 xv = *(const f32x4*)(&xs[t][d]);
      const f32x4 wv = *(const f32x4*)(&was[e][d]);
      acc4 += xv * wv;
    }
  }

  const float a = acc4[0] + acc4[1] + acc4[2] + acc4[3];
  aff[t][e] = 1.f / (1.f + expf(-a));
  __syncthreads();

  if (e == 0) {
    float b0 = -1e30f, b1 = -1e30f; int i0 = 0, i1 = 0;
    for (int i = 0; i < NE; i++) {
      const float v = aff[t][i];
      if (v > b0) { b1 = b0; i1 = i0; b0 = v; i0 = i; }
      else if (v > b1) { b1 = v; i1 = i; }
    }
    const int tok = t0 + t;
    const float inv = 1.f / (b0 + b1);
    topk_w[tok * 2] = b0 * inv;  topk_w[tok * 2 + 1] = b1 * inv;
    topk_i[tok * 2] = i0;        topk_i[tok * 2 + 1] = i1;
    atomicAdd(&cnt[i0], 1);      atomicAdd(&cnt[i1], 1);
  }
}

__global__ void prefix_kernel(const int* __restrict__ cnt, int* __restrict__ base) {
  if (threadIdx.x == 0) {
    int acc = 0;
    for (int e = 0; e < NE; e++) { base[e] = acc; acc += (cnt[e] + 127) & ~127; }
    base[NE] = SH_BASE;
    base[NE + 1] = SH_BASE + TOKENS;
  }
}

__global__ void build_lists_kernel(const int* __restrict__ topk_i, const int* __restrict__ base,
                                   int* __restrict__ pos, int* __restrict__ list,
                                   int* __restrict__ token_slot) {
  const int t = blockIdx.x * 256 + threadIdx.x;
  if (t >= TOKENS) return;
#pragma unroll
  for (int k = 0; k < 2; k++) {
    const int e = topk_i[t * 2 + k];
    const int p = atomicAdd(&pos[e], 1);
    const int slot = base[e] + p;
    list[slot] = t;
    token_slot[t * 2 + k] = slot;
  }
  list[SH_BASE + t] = t;
  list[SH_BASE + TOKENS + t] = t;
}

// ===== balanced per-expert XCD-chunked tile map (round-4/7 verified) =====
#define GEMM_GRID_MAX 2304   // 16 * (80 routed-max + 64 shared) m-tiles

__device__ __forceinline__ bool map_tile(int flat, const int* __restrict__ cnt,
                                         int& e, int& my, int& nx) {
  int o = 0;
  for (int ee = 0; ee < NE + 2; ++ee) {
    const int ce = (ee < NE) ? cnt[ee] : TOKENS;
    const int me = (ce + 127) >> 7;
    const int Te = me << 4;
    if (flat < o + Te) {
      const int l = flat - o;
      const int s = (l & 7) * (me << 1) + (l >> 3);
      nx = s / me;
      my = s - nx * me;
      e = ee;
      return true;
    }
    o += Te;
  }
  return false;
}

// ================= 2-phase 128x128 GEMMs, BK=32, 4 blocks/CU =================
// Verified round-9 structure (2-phase dbuf, BK=32 swizzle, 0 conflicts,
// launch_bounds(256,4)). NOTE: (256,5) forces VGPR cap 48 < 64-reg
// accumulator -> scratch spill (round-10: 1.16 GB writes, 6% MfmaUtil).
// Keep 4.

// ---------------- GEMM1: fused gate/up B1 ----------------
__global__ __launch_bounds__(256, 4) void gemm1_kernel(
    const bf16* __restrict__ xb, const int* __restrict__ list,
    const int* __restrict__ base, const int* __restrict__ cnt,
    const bf16* __restrict__ B1R, const bf16* __restrict__ B1S,
    const float* __restrict__ rgb, const float* __restrict__ rb1,
    const float* __restrict__ sgb, const float* __restrict__ sb1,
    bf16* __restrict__ H) {
  int e, bmy, bnx;
  if (!map_tile(blockIdx.x, cnt, e, bmy, bnx)) return;
  const int ce = (e < NE) ? cnt[e] : TOKENS;
  const int m0 = bmy * 128;
  const int n0 = bnx * 128;          // over 2*FF fused rows
  const int bse = base[e];

  const bf16* B1; const float *gb, *ub;
  if (e < NE) { B1 = B1R + (size_t)e * (2 * FF) * DM; gb = rgb + e * FF; ub = rb1 + e * FF; }
  else { const int s = e - NE; B1 = B1S + (size_t)s * (2 * FF) * DM; gb = sgb + s * FF; ub = sb1 + s * FF; }

  __shared__ bf16 As[2][128 * 32];   // 16 KB
  __shared__ bf16 Bs[2][128 * 32];   // 16 KB

  const int tid = threadIdx.x, lane = tid & 63, wid = tid >> 6;
  const int m16 = lane & 15, quad = lane >> 4;
  const int wm = (wid & 1) * 64, wn = (wid >> 1) * 64;
  const int rslot = (quad ^ ((m16 >> 1) & 3)) << 3;   // swizzled ds_read granule (elems)

  // staging: thread covers rows srow and 64+srow (granule tid&3)
  const int srow = tid >> 2;                          // 0..63
  const int gsw = (((tid & 3) ^ ((tid >> 3) & 3)) << 3);  // pre-swizzled source granule
  int ra0 = m0 + srow;      if (ra0 >= ce) ra0 = ce - 1;
  int ra1 = m0 + 64 + srow; if (ra1 >= ce) ra1 = ce - 1;
  const bf16* aP0 = xb + (size_t)list[bse + ra0] * DM + gsw;
  const bf16* aP1 = xb + (size_t)list[bse + ra1] * DM + gsw;
  const bf16* bP0 = B1 + (size_t)(n0 + srow) * DM + gsw;
  const bf16* bP1 = B1 + (size_t)(n0 + 64 + srow) * DM + gsw;
  const int d0 = wid * 512;            // wave LDS base, sweep 0 (elems)
  const int d1 = 2048 + wid * 512;     // sweep 1
  const int l8 = lane << 3;

#define G1_STAGE(buf, k)                              \
  {                                                   \
    load_lds16(aP0 + (k), &As[buf][d0 + l8]);         \
    load_lds16(aP1 + (k), &As[buf][d1 + l8]);         \
    load_lds16(bP0 + (k), &Bs[buf][d0 + l8]);         \
    load_lds16(bP1 + (k), &Bs[buf][d1 + l8]);         \
  }

  f32x4 acc[4][4] = {};

  G1_STAGE(0, 0)

  int cur = 0;
  for (int k0 = 0; k0 < DM; k0 += 32) {
    __syncthreads();                 // drains vmcnt -> buf(cur) ready; reads of buf(nxt) done
    if (k0 + 32 < DM) { G1_STAGE(cur ^ 1, k0 + 32) }
    bf16x8 af[4], bfr[4];
#pragma unroll
    for (int i = 0; i < 4; i++) {
      af[i]  = *(const bf16x8*)(&As[cur][(wm + m16 + 16 * i) * 32 + rslot]);
      bfr[i] = *(const bf16x8*)(&Bs[cur][(wn + m16 + 16 * i) * 32 + rslot]);
    }
#pragma unroll
    for (int mi = 0; mi < 4; mi++)
#pragma unroll
      for (int ni = 0; ni < 4; ni++)
        acc[mi][ni] = __builtin_amdgcn_mfma_f32_16x16x32_bf16(af[mi], bfr[ni], acc[mi][ni], 0, 0, 0);
    cur ^= 1;
  }
#undef G1_STAGE

  // epilogue: ni even = gate, ni odd = up, same f range; h = gelu(g)*u
  const int q4 = quad * 4;
  const int fbase = ((n0 + wn) >> 1) + m16;
#pragma unroll
  for (int mi = 0; mi < 4; mi++) {
#pragma unroll
    for (int nj = 0; nj < 2; nj++) {
      const int f = fbase + nj * 16;
      const float gbv = gb[f], ubv = ub[f];
#pragma unroll
      for (int r = 0; r < 4; r++) {
        const int row = m0 + wm + mi * 16 + q4 + r;
        const float g = acc[mi][2 * nj][r] + gbv;
        const float u = acc[mi][2 * nj + 1][r] + ubv;
        const float h = 0.5f * g * (1.f + erff(g * 0.70710678118f)) * u;
        H[(size_t)(bse + row) * FF + f] = f2bf(h);
      }
    }
  }
}

// ---------------- GEMM2: Y = H @ w2 + b2 ----------------
__global__ __launch_bounds__(256, 4) void gemm2_kernel(
    const bf16* __restrict__ Hb, const int* __restrict__ base, const int* __restrict__ cnt,
    const bf16* __restrict__ rw2T, const bf16* __restrict__ sw2T,
    const float* __restrict__ rb2, const float* __restrict__ sb2,
    bf16* __restrict__ Y) {
  int e, bmy, bnx;
  if (!map_tile(blockIdx.x, cnt, e, bmy, bnx)) return;
  const int m0 = bmy * 128;
  const int n0 = bnx * 128;
  const int bse = base[e];

  const bf16* B; const float* bb;
  if (e < NE) { B = rw2T + (size_t)e * DM * FF; bb = rb2 + e * DM; }
  else { const int s = e - NE; B = sw2T + (size_t)s * DM * FF; bb = sb2 + s * DM; }

  __shared__ bf16 As[2][128 * 32];
  __shared__ bf16 Bs[2][128 * 32];

  const int tid = threadIdx.x, lane = tid & 63, wid = tid >> 6;
  const int m16 = lane & 15, quad = lane >> 4;
  const int wm = (wid & 1) * 64, wn = (wid >> 1) * 64;
  const int rslot = (quad ^ ((m16 >> 1) & 3)) << 3;

  const int srow = tid >> 2;
  const int gsw = (((tid & 3) ^ ((tid >> 3) & 3)) << 3);
  const bf16* aP0 = Hb + (size_t)(bse + m0 + srow) * FF + gsw;       // padded rows valid
  const bf16* aP1 = Hb + (size_t)(bse + m0 + 64 + srow) * FF + gsw;
  const bf16* bP0 = B + (size_t)(n0 + srow) * FF + gsw;
  const bf16* bP1 = B + (size_t)(n0 + 64 + srow) * FF + gsw;
  const int d0 = wid * 512;
  const int d1 = 2048 + wid * 512;
  const int l8 = lane << 3;

#define G2_STAGE(buf, k)                              \
  {                                                   \
    load_lds16(aP0 + (k), &As[buf][d0 + l8]);         \
    load_lds16(aP1 + (k), &As[buf][d1 + l8]);         \
    load_lds16(bP0 + (k), &Bs[buf][d0 + l8]);         \
    load_lds16(bP1 + (k), &Bs[buf][d1 + l8]);         \
  }

  f32x4 acc[4][4] = {};

  G2_STAGE(0, 0)

  int cur = 0;
  for (int k0 = 0; k0 < FF; k0 += 32) {
    __syncthreads();
    if (k0 + 32 < FF) { G2_STAGE(cur ^ 1, k0 + 32) }
    bf16x8 af[4], bfr[4];
#pragma unroll
    for (int i = 0; i < 4; i++) {
      af[i]  = *(const bf16x8*)(&As[cur][(wm + m16 + 16 * i) * 32 + rslot]);
      bfr[i] = *(const bf16x8*)(&Bs[cur][(wn + m16 + 16 * i) * 32 + rslot]);
    }
#pragma unroll
    for (int mi = 0; mi < 4; mi++)
#pragma unroll
      for (int ni = 0; ni < 4; ni++)
        acc[mi][ni] = __builtin_amdgcn_mfma_f32_16x16x32_bf16(af[mi], bfr[ni], acc[mi][ni], 0, 0, 0);
    cur ^= 1;
  }
#undef G2_STAGE

  const int q4 = quad * 4;
#pragma unroll
  for (int mi = 0; mi < 4; mi++) {
#pragma unroll
    for (int ni = 0; ni < 4; ni++) {
      const int n = n0 + wn + ni * 16 + m16;
      const float bv = bb[n];
#pragma unroll
      for (int r = 0; r < 4; r++) {
        const int row = m0 + wm + mi * 16 + q4 + r;
        Y[(size_t)(bse + row) * DM + n] = f2bf(acc[mi][ni][r] + bv);
      }
    }
  }
}

// ---------------- combine ----------------
__global__ void combine_kernel(const float* __restrict__ x, const bf16* __restrict__ Y,
                               const int* __restrict__ token_slot, const float* __restrict__ topk_w,
                               float* __restrict__ out) {
  const int t = blockIdx.x;
  const int d = threadIdx.x * 8;
  const int s0 = token_slot[t * 2], s1 = token_slot[t * 2 + 1];
  const float w0 = topk_w[t * 2], w1 = topk_w[t * 2 + 1];
  const bf16x8 ya = *(const bf16x8*)(Y + (size_t)(SH_BASE + t) * DM + d);
  const bf16x8 yb = *(const bf16x8*)(Y + (size_t)(SH_BASE + TOKENS + t) * DM + d);
  const bf16x8 y0 = *(const bf16x8*)(Y + (size_t)s0 * DM + d);
  const bf16x8 y1 = *(const bf16x8*)(Y + (size_t)s1 * DM + d);
  const float* xp = x + (size_t)t * DM + d;
  float* op = out + (size_t)t * DM + d;
#pragma unroll
  for (int j = 0; j < 8; j++)
    op[j] = xp[j] + (float)ya[j] + (float)yb[j] + w0 * (float)y0[j] + w1 * (float)y1[j];
}

extern "C" void kernel_launch(void* const* d_in, const int* in_sizes, int n_in,
                              void* d_out, int out_size, void* d_ws, size_t ws_size,
                              hipStream_t stream) {
  (void)in_sizes; (void)n_in; (void)out_size; (void)ws_size;
  const float* x   = (const float*)d_in[0];
  const float* wa  = (const float*)d_in[1];
  const float* rg  = (const float*)d_in[2];
  const float* rgb = (const float*)d_in[3];
  const float* rw1 = (const float*)d_in[4];
  const float* rb1 = (const float*)d_in[5];
  const float* rw2 = (const float*)d_in[6];
  const float* rb2 = (const float*)d_in[7];
  const float* sg  = (const float*)d_in[8];
  const float* sgb = (const float*)d_in[9];
  const float* sw1 = (const float*)d_in[10];
  const float* sb1 = (const float*)d_in[11];
  const float* sw2 = (const float*)d_in[12];
  const float* sb2 = (const float*)d_in[13];
  float* out = (float*)d_out;

  char* ws = (char*)d_ws;
  int*   cnt        = (int*)(ws + WS_CNT);
  int*   pos        = (int*)(ws + WS_POS);
  int*   basep      = (int*)(ws + WS_BASE);
  float* topk_w     = (float*)(ws + WS_TOPKW);
  int*   topk_i     = (int*)(ws + WS_TOPKI);
  int*   token_slot = (int*)(ws + WS_TSLOT);
  int*   list       = (int*)(ws + WS_LIST);
  bf16*  xb         = (bf16*)(ws + WS_XB);
  bf16*  H          = (bf16*)(ws + WS_H);
  bf16*  Y          = (bf16*)(ws + WS_Y);
  bf16*  B1R        = (bf16*)(ws + WS_B1R);
  bf16*  B1S        = (bf16*)(ws + WS_B1S);
  bf16*  W2TR       = (bf16*)(ws + WS_W2TR);
  bf16*  W2TS       = (bf16*)(ws + WS_W2TS);

  hipMemsetAsync(ws, 0, 128, stream);  // cnt + pos

  router_kernel<<<TOKENS / RT_TOK, 256, 0, stream>>>(x, wa, topk_w, topk_i, cnt, xb);
  prefix_kernel<<<1, 64, 0, stream>>>(cnt, basep);
  build_lists_kernel<<<TOKENS / 256, 256, 0, stream>>>(topk_i, basep, pos, list, token_slot);

  // weight prep (merged): fused gate/up -> B1, plain transpose -> W2T
  transpose_cvt_fused_all_kernel<<<dim3(FF / 64, DM / 64, 36), 256, 0, stream>>>(
      rg, rw1, sg, sw1, B1R, B1S);
  transpose_cvt_all_kernel<<<dim3(DM / 64, FF / 64, 18), 256, 0, stream>>>(
      rw2, sw2, W2TR, W2TS);

  gemm1_kernel<<<GEMM_GRID_MAX, 256, 0, stream>>>(
      xb, list, basep, cnt, B1R, B1S, rgb, rb1, sgb, sb1, H);
  gemm2_kernel<<<GEMM_GRID_MAX, 256, 0, stream>>>(
      H, basep, cnt, W2TR, W2TS, rb2, sb2, Y);
  combine_kernel<<<TOKENS, 256, 0, stream>>>(x, Y, token_slot, topk_w, out);
}